// Round 10
// baseline (24.297 us; speedup 1.0000x reference)
//
#include <hip/hip_runtime.h>

#define NN 512

// Single fused kernel. Block = (4-row band rb) x (64-col tile jt).
// 4 waves split the k-span [i0, (jt+1)*64) into 4 equal chunks (span % 4 == 0),
// each accumulates partials for 4 rows x 64 cols, LDS-reduce, store.
// Below-diagonal blocks store zeros. Masks make j<i outputs exactly 0.
__global__ __launch_bounds__(256) void ut_fused(const float* __restrict__ A,
                                                const float* __restrict__ B,
                                                float* __restrict__ C) {
    const int jt   = (int)blockIdx.x;        // 0..7   column tile
    const int rb   = (int)blockIdx.y;        // 0..127 row band (4 rows)
    const int w    = (int)threadIdx.x >> 6;  // wave 0..3
    const int lane = (int)threadIdx.x & 63;
    const int i0   = rb << 2;
    const int it   = i0 >> 6;                // row tile of this band
    const int j    = (jt << 6) + lane;

    if (jt < it) {                           // strictly below diagonal
        C[(i0 + w) * NN + j] = 0.0f;
        return;
    }

    __shared__ float red[4][4][64];          // [wave][row][col]

    // per-row A pointers: pA[r][k] == A(i0+r, k), valid for k >= i0+r
    const float* pA[4];
    #pragma unroll
    for (int r = 0; r < 4; ++r) {
        const int ir = i0 + r;
        pA[r] = A + (((ir * (2 * NN - ir + 1)) >> 1) - ir);
    }

    // k-chunk for this wave
    const int kbeg = i0;
    const int kend = (jt + 1) << 6;
    const int L    = (kend - kbeg) >> 2;     // span divisible by 4
    const int k0   = kbeg + w * L;
    const int k1   = k0 + L;

    int idxB = ((k0 * (2 * NN - k0 + 1)) >> 1) + (j - k0);  // B(k0, j)

    float acc0 = 0.f, acc1 = 0.f, acc2 = 0.f, acc3 = 0.f;
    #pragma unroll 4
    for (int k = k0; k < k1; ++k) {
        const float bv = (k <= j) ? B[idxB] : 0.0f;          // per-lane mask
        const float a0 = (k >= i0)     ? pA[0][k] : 0.0f;    // wave-uniform masks
        const float a1 = (k >= i0 + 1) ? pA[1][k] : 0.0f;
        const float a2 = (k >= i0 + 2) ? pA[2][k] : 0.0f;
        const float a3 = (k >= i0 + 3) ? pA[3][k] : 0.0f;
        acc0 += a0 * bv;
        acc1 += a1 * bv;
        acc2 += a2 * bv;
        acc3 += a3 * bv;
        idxB += NN - 1 - k;
    }

    red[w][0][lane] = acc0;
    red[w][1][lane] = acc1;
    red[w][2][lane] = acc2;
    red[w][3][lane] = acc3;
    __syncthreads();

    // 256 threads = (row w) x (col lane): sum the 4 waves' partials
    const float s = (red[0][w][lane] + red[1][w][lane]) +
                    (red[2][w][lane] + red[3][w][lane]);
    C[(i0 + w) * NN + j] = s;
}

extern "C" void kernel_launch(void* const* d_in, const int* in_sizes, int n_in,
                              void* d_out, int out_size, void* d_ws, size_t ws_size,
                              hipStream_t stream) {
    const float* A = (const float*)d_in[0];
    const float* B = (const float*)d_in[1];
    float* C = (float*)d_out;
    ut_fused<<<dim3(8, 128), dim3(256), 0, stream>>>(A, B, C);
}

// Round 11
// 22.541 us; speedup vs baseline: 1.0779x; 1.0779x over previous
//
#include <hip/hip_runtime.h>

#define NN 512

// Block = (8-row band) x (64-col tile jt). 8 waves (512 thr) split the k-span
// [i0, (jt+1)*64) into 8 equal chunks (span % 8 == 0). 3-phase loop keeps the
// interior unmasked. 16 KB LDS reduce, one barrier, single dispatch.
__global__ __launch_bounds__(512) void ut_fused8(const float* __restrict__ A,
                                                 const float* __restrict__ B,
                                                 float* __restrict__ C) {
    const int jt   = (int)blockIdx.x;        // 0..7   column tile
    const int band = (int)blockIdx.y;        // 0..63  row band (8 rows)
    const int w    = (int)threadIdx.x >> 6;  // wave 0..7
    const int lane = (int)threadIdx.x & 63;
    const int i0   = band << 3;
    const int it   = band >> 3;              // row tile of this band
    const int j    = (jt << 6) + lane;

    if (jt < it) {                           // strictly below diagonal: 8x64 zeros
        C[(i0 + w) * NN + j] = 0.0f;
        return;
    }

    __shared__ float red[8][8][64];          // [wave][row][col] = 16 KB

    // pA[r][k] == A(i0+r, k), valid for k >= i0+r
    const float* pA[8];
    #pragma unroll
    for (int r = 0; r < 8; ++r) {
        const int ir = i0 + r;
        pA[r] = A + (((ir * (2 * NN - ir + 1)) >> 1) - ir);
    }

    const int kend = (jt + 1) << 6;
    const int L    = (kend - i0) >> 3;       // span divisible by 8
    const int k0   = i0 + w * L;
    const int k1   = k0 + L;

    int idxB = ((k0 * (2 * NN - k0 + 1)) >> 1) + (j - k0);  // B(k0, j)

    float acc[8];
    #pragma unroll
    for (int r = 0; r < 8; ++r) acc[r] = 0.f;

    int k = k0;
    if (jt == it) {
        // diagonal block: full masks (short: L <= 8)
        for (; k < k1; ++k) {
            const float bv = (k <= j) ? B[idxB] : 0.f;
            #pragma unroll
            for (int r = 0; r < 8; ++r) {
                const float av = (k >= i0 + r) ? pA[r][k] : 0.f;
                acc[r] += av * bv;
            }
            idxB += NN - 1 - k;
        }
    } else {
        // phase 1: A-masked head, k < i0+8 (B unmasked: i0+8 <= jt*64 here)
        const int kaE = (k1 < i0 + 8) ? k1 : (i0 + 8);
        for (; k < kaE; ++k) {
            const float bv = B[idxB];
            #pragma unroll
            for (int r = 0; r < 8; ++r) {
                const float av = (k >= i0 + r) ? pA[r][k] : 0.f;
                acc[r] += av * bv;
            }
            idxB += NN - 1 - k;
        }
        // phase 2: unmasked interior, k < jt*64
        const int jtd = jt << 6;
        const int kiE = (k1 < jtd) ? k1 : jtd;
        #pragma unroll 8
        for (; k < kiE; ++k) {
            const float bv = B[idxB];
            #pragma unroll
            for (int r = 0; r < 8; ++r) acc[r] += pA[r][k] * bv;
            idxB += NN - 1 - k;
        }
        // phase 3: diagonal-tile tail, B-masked (A rows all valid: k >= jtd > i0+7)
        for (; k < k1; ++k) {
            const float bv = (k <= j) ? B[idxB] : 0.f;
            #pragma unroll
            for (int r = 0; r < 8; ++r) acc[r] += pA[r][k] * bv;
            idxB += NN - 1 - k;
        }
    }

    #pragma unroll
    for (int r = 0; r < 8; ++r) red[w][r][lane] = acc[r];
    __syncthreads();

    // thread (row w, col lane) sums the 8 waves' partials in wave order
    float s = 0.f;
    #pragma unroll
    for (int t = 0; t < 8; ++t) s += red[t][w][lane];
    C[(i0 + w) * NN + j] = s;
}

extern "C" void kernel_launch(void* const* d_in, const int* in_sizes, int n_in,
                              void* d_out, int out_size, void* d_ws, size_t ws_size,
                              hipStream_t stream) {
    const float* A = (const float*)d_in[0];
    const float* B = (const float*)d_in[1];
    float* C = (float*)d_out;
    ut_fused8<<<dim3(8, 64), dim3(512), 0, stream>>>(A, B, C);
}